// Round 2
// baseline (340.904 us; speedup 1.0000x reference)
//
#include <hip/hip_runtime.h>

// out[b,i,f] = X[b,0,i,i,f] + sum_j A[b,i,j] * (X[b,1,i,j,f]+X[b,2,i,j,f]+X[b,3,i,j,f])
// A: (4,256,256) f32, X: (4,4,256,256,64) f32, out: (4,256,64) f32
//
// Traffic floor: hops 1..3 of X (192 MiB) + A (1 MiB) + diag of hop 0 (0.25 MiB)
// read, 0.25 MiB write -> ~31 us at 6.3 TB/s. Memory-bound; hop-0 slab skipped.

constexpr int N   = 256;
constexpr int F   = 64;
constexpr int F4  = F / 4;   // 16 float4 per row
constexpr int KP1 = 4;

__global__ __launch_bounds__(256) void gnn_kernel(const float* __restrict__ A,
                                                  const float* __restrict__ X,
                                                  float* __restrict__ out) {
    // one block per (b, i)
    const int bi = blockIdx.x;          // 0..1023
    const int b  = bi >> 8;
    const int i  = bi & (N - 1);
    const int t  = threadIdx.x;         // 0..255
    const int f4 = t & (F4 - 1);        // 0..15  (float4 index in F)
    const int j0 = t >> 4;              // 0..15  (j-group)

    __shared__ float  sA[N];
    __shared__ float4 sPart[64];        // 4 partials per f4 after intra-wave reduce

    // stage A row into LDS (1 KiB, one coalesced load per block)
    sA[t] = A[(size_t)b * N * N + (size_t)i * N + t];
    __syncthreads();

    const size_t kstride = (size_t)N * N * F;   // elements per hop slab
    const size_t bstride = (size_t)KP1 * kstride;
    const size_t istride = (size_t)N * F;       // one i-row: 256 j x 64 f

    const float* baseRow = X + (size_t)b * bstride + (size_t)i * istride;
    const float4* __restrict__ X1 = (const float4*)(baseRow + 1 * kstride);
    const float4* __restrict__ X2 = (const float4*)(baseRow + 2 * kstride);
    const float4* __restrict__ X3 = (const float4*)(baseRow + 3 * kstride);

    float4 acc = make_float4(0.f, 0.f, 0.f, 0.f);

    // wave (64 lanes) covers a contiguous 1 KiB segment per slab per iter
#pragma unroll 8
    for (int jj = 0; jj < N / 16; ++jj) {
        const int j   = j0 + jj * 16;
        const int idx = j * F4 + f4;
        const float a = sA[j];
        const float4 x1 = X1[idx];
        const float4 x2 = X2[idx];
        const float4 x3 = X3[idx];
        acc.x = fmaf(a, x1.x + x2.x + x3.x, acc.x);
        acc.y = fmaf(a, x1.y + x2.y + x3.y, acc.y);
        acc.z = fmaf(a, x1.z + x2.z + x3.z, acc.z);
        acc.w = fmaf(a, x1.w + x2.w + x3.w, acc.w);
    }

    // intra-wave reduce: lanes t and t^16, t^32 hold same f4, different j-groups.
    // butterfly over xor 16 and 32 leaves lanes 0..15 of each wave with the
    // wave's total for its f4.
    acc.x += __shfl_xor(acc.x, 16, 64);
    acc.y += __shfl_xor(acc.y, 16, 64);
    acc.z += __shfl_xor(acc.z, 16, 64);
    acc.w += __shfl_xor(acc.w, 16, 64);
    acc.x += __shfl_xor(acc.x, 32, 64);
    acc.y += __shfl_xor(acc.y, 32, 64);
    acc.z += __shfl_xor(acc.z, 32, 64);
    acc.w += __shfl_xor(acc.w, 32, 64);

    const int wave = t >> 6;            // 0..3
    const int lane = t & 63;
    if (lane < F4) {
        sPart[wave * F4 + lane] = acc;  // 4 partials per f4
    }
    __syncthreads();

    if (t < F4) {
        const float4 p0 = sPart[0 * F4 + t];
        const float4 p1 = sPart[1 * F4 + t];
        const float4 p2 = sPart[2 * F4 + t];
        const float4 p3 = sPart[3 * F4 + t];
        // hop-0 identity term: diagonal X[b,0,i,i,:]
        const float4 d = ((const float4*)(baseRow + (size_t)i * F))[t];
        float4 r;
        r.x = d.x + (p0.x + p1.x) + (p2.x + p3.x);
        r.y = d.y + (p0.y + p1.y) + (p2.y + p3.y);
        r.z = d.z + (p0.z + p1.z) + (p2.z + p3.z);
        r.w = d.w + (p0.w + p1.w) + (p2.w + p3.w);
        ((float4*)(out + (size_t)b * N * F + (size_t)i * F))[t] = r;
    }
}

extern "C" void kernel_launch(void* const* d_in, const int* in_sizes, int n_in,
                              void* d_out, int out_size, void* d_ws, size_t ws_size,
                              hipStream_t stream) {
    const float* A = (const float*)d_in[0];
    const float* X = (const float*)d_in[1];
    float* out = (float*)d_out;
    const int batch = 4;
    dim3 grid(batch * N);
    dim3 block(256);
    gnn_kernel<<<grid, block, 0, stream>>>(A, X, out);
}